// Round 1
// baseline (136.865 us; speedup 1.0000x reference)
//
#include <hip/hip_runtime.h>
#include <math.h>

#define NB   4      // n
#define C    128    // channels
#define S    31     // frames
#define HW   704    // h*w = 32*22
#define T    30     // s-1
#define NS   120    // n*(s-1)
#define K    16     // top_k

// ---------------------------------------------------------------------------
// Kernel 1: per-pixel channel contraction (1x1 conv, C->1) for both weight
// vectors. a[i][p] = dot(x[n,:,t,p], w1)+b1  (frames 0..T-1)
//          b[i][p] = dot(x[n,:,t+1,p], w2)+b2 (frames 1..T)
// One thread per (n, frame, pixel). Coalesced across p at every c.
// ---------------------------------------------------------------------------
__global__ __launch_bounds__(256) void conv_kernel(
    const float* __restrict__ x,
    const float* __restrict__ w1, const float* __restrict__ b1p,
    const float* __restrict__ w2, const float* __restrict__ b2p,
    float* __restrict__ A, float* __restrict__ B) {
  int pix = blockIdx.x * 256 + threadIdx.x;
  if (pix >= NB * S * HW) return;
  int p  = pix % HW;
  int sf = (pix / HW) % S;
  int n  = pix / (S * HW);
  const float* xp = x + (((size_t)n * C) * S + sf) * HW + p;
  float acc1 = 0.f, acc2 = 0.f;
#pragma unroll 8
  for (int c = 0; c < C; ++c) {
    float xv = xp[(size_t)c * S * HW];
    acc1 = fmaf(xv, w1[c], acc1);   // w1[c]/w2[c] are wave-uniform -> s_load
    acc2 = fmaf(xv, w2[c], acc2);
  }
  if (sf < T)  A[(n * T + sf) * HW + p]       = acc1 + b1p[0];
  if (sf >= 1) B[(n * T + (sf - 1)) * HW + p] = acc2 + b2p[0];
}

// ---------------------------------------------------------------------------
// Kernel 2: per frame-pair i, extract the 16 largest values of b_i
// (descending) and the 16 smallest (ascending) via iterative block argmax.
// 120 blocks x 256 threads; two LDS copies so -inf/+inf marking doesn't
// cross-contaminate the min pass.
// ---------------------------------------------------------------------------
__global__ __launch_bounds__(256) void topbot_kernel(
    const float* __restrict__ B,
    float* __restrict__ btop, float* __restrict__ bbot) {
  const int i   = blockIdx.x;
  const int tid = threadIdx.x;
  __shared__ float smax[HW];
  __shared__ float smin[HW];
  __shared__ float rv[4];
  __shared__ int   ri[4];
  const float* bi = B + i * HW;
  for (int q = tid; q < HW; q += 256) {
    float v = bi[q];
    smax[q] = v;
    smin[q] = v;
  }
  __syncthreads();
  const int lane = tid & 63;
  const int wv   = tid >> 6;

  // 16 maxima, descending
  for (int j = 0; j < K; ++j) {
    float best = -INFINITY; int bidx = 0;
    for (int q = tid; q < HW; q += 256) {
      float v = smax[q];
      if (v > best) { best = v; bidx = q; }
    }
    for (int off = 32; off > 0; off >>= 1) {
      float ov = __shfl_down(best, off, 64);
      int   oi = __shfl_down(bidx, off, 64);
      if (ov > best) { best = ov; bidx = oi; }
    }
    if (lane == 0) { rv[wv] = best; ri[wv] = bidx; }
    __syncthreads();
    if (tid == 0) {
      float bb = rv[0]; int bx = ri[0];
      for (int t = 1; t < 4; ++t) if (rv[t] > bb) { bb = rv[t]; bx = ri[t]; }
      btop[i * K + j] = bb;
      smax[bx] = -INFINITY;
    }
    __syncthreads();
  }

  // 16 minima, ascending
  for (int j = 0; j < K; ++j) {
    float best = INFINITY; int bidx = 0;
    for (int q = tid; q < HW; q += 256) {
      float v = smin[q];
      if (v < best) { best = v; bidx = q; }
    }
    for (int off = 32; off > 0; off >>= 1) {
      float ov = __shfl_down(best, off, 64);
      int   oi = __shfl_down(bidx, off, 64);
      if (ov < best) { best = ov; bidx = oi; }
    }
    if (lane == 0) { rv[wv] = best; ri[wv] = bidx; }
    __syncthreads();
    if (tid == 0) {
      float bb = rv[0]; int bx = ri[0];
      for (int t = 1; t < 4; ++t) if (rv[t] < bb) { bb = rv[t]; bx = ri[t]; }
      bbot[i * K + j] = bb;
      smin[bx] = INFINITY;
    }
    __syncthreads();
  }
}

// ---------------------------------------------------------------------------
// Kernel 3: one thread per attention row (i, q-row index called "row" here).
// denom = sum_q exp(a*b_q - m), m = a>=0 ? a*max(b) : a*min(b).
// Top-16 softmax values = exp(a*b_sel[j] - m)/denom with b_sel = top16
// (a>=0) or bot16 (a<0). a==0 degenerates to uniform 1/704 automatically.
// The reference's raw reshape (ns,hw,k)->(ns,k,h,w) means row q's 16 values
// land at frame-flat f = q*16+jj -> (j_out=q/44, p_out=(q%44)*16+jj):
// 16 contiguous floats, 64B aligned -> 4x float4 stores.
// ---------------------------------------------------------------------------
__global__ __launch_bounds__(256) void softmax_topk_kernel(
    const float* __restrict__ A, const float* __restrict__ B,
    const float* __restrict__ btop, const float* __restrict__ bbot,
    float* __restrict__ out) {
  const int i   = blockIdx.y;               // frame pair 0..119
  const int row = blockIdx.x * 256 + threadIdx.x;
  if (row >= HW) return;

  // wave-uniform loads of the selection lists -> SGPRs
  float st[K], sb[K];
#pragma unroll
  for (int j = 0; j < K; ++j) {
    st[j] = btop[i * K + j];
    sb[j] = bbot[i * K + j];
  }

  const float av   = A[i * HW + row];
  const float m    = (av >= 0.f) ? av * st[0] : av * sb[0];
  const float negm = -m;

  const float* __restrict__ bi = B + i * HW;  // wave-uniform address stream
  float denom = 0.f;
#pragma unroll 8
  for (int q = 0; q < HW; ++q) {
    denom += __expf(fmaf(av, bi[q], negm));
  }
  const float inv = 1.0f / denom;

  float v[K];
#pragma unroll
  for (int jj = 0; jj < K; ++jj) {
    float sel = (av >= 0.f) ? st[jj] : sb[jj];
    v[jj] = __expf(fmaf(av, sel, negm)) * inv;
  }

  const int n  = i / T;
  const int t  = i % T;
  const int jo = row / 44;             // 704/16 = 44 rows per output j-slice
  const int po = (row % 44) * K;
  float* op = out + ((((size_t)n * K + jo) * T) + t) * HW + po;
  float4* o4 = reinterpret_cast<float4*>(op);
  o4[0] = make_float4(v[0],  v[1],  v[2],  v[3]);
  o4[1] = make_float4(v[4],  v[5],  v[6],  v[7]);
  o4[2] = make_float4(v[8],  v[9],  v[10], v[11]);
  o4[3] = make_float4(v[12], v[13], v[14], v[15]);
}

extern "C" void kernel_launch(void* const* d_in, const int* in_sizes, int n_in,
                              void* d_out, int out_size, void* d_ws, size_t ws_size,
                              hipStream_t stream) {
  (void)in_sizes; (void)n_in; (void)out_size; (void)ws_size;
  const float* x  = (const float*)d_in[0];
  const float* w1 = (const float*)d_in[1];
  const float* b1 = (const float*)d_in[2];
  const float* w2 = (const float*)d_in[3];
  const float* b2 = (const float*)d_in[4];
  // d_in[5] is top_k (=16), hardcoded as K.
  float* out = (float*)d_out;

  float* A    = (float*)d_ws;            // NS*HW
  float* B    = A + NS * HW;             // NS*HW
  float* btop = B + NS * HW;             // NS*K
  float* bbot = btop + NS * K;           // NS*K

  const int npix = NB * S * HW;
  conv_kernel<<<(npix + 255) / 256, 256, 0, stream>>>(x, w1, b1, w2, b2, A, B);
  topbot_kernel<<<NS, 256, 0, stream>>>(B, btop, bbot);
  dim3 g3((HW + 255) / 256, NS);
  softmax_topk_kernel<<<g3, 256, 0, stream>>>(A, B, btop, bbot, out);
}

// Round 3
// 127.513 us; speedup vs baseline: 1.0733x; 1.0733x over previous
//
#include <hip/hip_runtime.h>
#include <math.h>

#define NB   4      // n
#define C    128    // channels
#define S    31     // frames
#define HW   704    // h*w = 32*22
#define T    30     // s-1
#define NS   120    // n*(s-1)
#define K    16     // top_k

// ---------------------------------------------------------------------------
// Kernel 1: 1x1 conv (C->1) for both weight vectors, 4-way channel split.
// Block = 256 threads = 64 pixels x 4 channel-groups of 32. Each thread does
// 32 coalesced loads (lanes of a wave share a c-group, cover 64 consecutive
// pixels). LDS combine across the 4 partial sums. 1364 blocks -> 5456 waves
// (~5.3/SIMD): hides HBM latency, BW-bound.
// ---------------------------------------------------------------------------
__global__ __launch_bounds__(256) void conv_kernel(
    const float* __restrict__ x,
    const float* __restrict__ w1, const float* __restrict__ b1p,
    const float* __restrict__ w2, const float* __restrict__ b2p,
    float* __restrict__ A, float* __restrict__ B) {
  const int tid   = threadIdx.x;
  const int chunk = blockIdx.x % 11;       // 11 chunks of 64 pixels = 704
  const int fr    = blockIdx.x / 11;       // 0..123 = (n, sf)
  const int sf    = fr % S;
  const int n     = fr / S;
  const int p     = chunk * 64 + (tid & 63);
  const int cg    = tid >> 6;              // 0..3

  const float* xp = x + (((size_t)(n * C + cg * 32) * S + sf) * HW) + p;
  const float* wA = w1 + cg * 32;
  const float* wB = w2 + cg * 32;
  float acc1 = 0.f, acc2 = 0.f;
#pragma unroll
  for (int c = 0; c < 32; ++c) {
    float xv = xp[(size_t)c * (S * HW)];
    acc1 = fmaf(xv, wA[c], acc1);
    acc2 = fmaf(xv, wB[c], acc2);
  }
  __shared__ float s1[256], s2[256];
  s1[tid] = acc1;
  s2[tid] = acc2;
  __syncthreads();
  if (tid < 64) {
    float a1 = (s1[tid] + s1[tid + 64]) + (s1[tid + 128] + s1[tid + 192]);
    float a2 = (s2[tid] + s2[tid + 64]) + (s2[tid + 128] + s2[tid + 192]);
    if (sf < T)  A[(n * T + sf) * HW + p]       = a1 + b1p[0];
    if (sf >= 1) B[(n * T + (sf - 1)) * HW + p] = a2 + b2p[0];
  }
}

// ---------------------------------------------------------------------------
// Kernel 2: full bitonic sort (ascending) of each frame-pair's 704 b-values,
// padded to 1024 with +INF. One block of 512 threads per frame pair,
// 2 elements/thread, 55 compare-exchange passes.
// bottom-16 asc = s[0..15]; top-16 desc = s[703], s[702], ...
// ---------------------------------------------------------------------------
__global__ __launch_bounds__(512) void sort_kernel(
    const float* __restrict__ B,
    float* __restrict__ btop, float* __restrict__ bbot) {
  __shared__ float s[1024];
  const int i   = blockIdx.x;
  const int tid = threadIdx.x;
  const float* bi = B + i * HW;
  for (int q = tid; q < 1024; q += 512)
    s[q] = (q < HW) ? bi[q] : INFINITY;
  __syncthreads();
#pragma unroll 1
  for (int k = 2; k <= 1024; k <<= 1) {
#pragma unroll 1
    for (int j = k >> 1; j > 0; j >>= 1) {
#pragma unroll
      for (int idx = tid; idx < 1024; idx += 512) {
        int ixj = idx ^ j;
        if (ixj > idx) {
          float a = s[idx], b = s[ixj];
          if ((a > b) == ((idx & k) == 0)) { s[idx] = b; s[ixj] = a; }
        }
      }
      __syncthreads();
    }
  }
  if (tid < K) {
    bbot[i * K + tid] = s[tid];            // 16 smallest, ascending
    btop[i * K + tid] = s[HW - 1 - tid];   // 16 largest, descending
  }
}

// ---------------------------------------------------------------------------
// Kernel 3: ONE WAVE PER ATTENTION ROW. Grid = NS*HW/4 = 21120 blocks x 4
// waves (R2 bug: launched /256 grid -> only 1320 of 84480 rows written).
// Lane l covers q = j*64+l (coalesced b reads), butterfly shuffle-reduce for
// the denominator. ln2 folded into the fma -> native exp2f. m = exact row
// max of a*b so every exponent <= 0. Lanes 0..15 write the 16 contiguous
// output floats: raw-reshape f = r*16+jj -> (j_out=r/44, p_out=(r%44)*16+jj).
// ---------------------------------------------------------------------------
__global__ __launch_bounds__(256) void softmax_topk_kernel(
    const float* __restrict__ A, const float* __restrict__ B,
    const float* __restrict__ btop, const float* __restrict__ bbot,
    float* __restrict__ out) {
  const int lane = threadIdx.x & 63;
  const int R    = blockIdx.x * 4 + (threadIdx.x >> 6);  // row 0..84479
  const int i    = R / HW;
  const int r    = R % HW;

  const float av  = A[R];
  const float st0 = btop[i * K];
  const float sb0 = bbot[i * K];
  const float m   = (av >= 0.f) ? av * st0 : av * sb0;
  const float L2E   = 1.4426950408889634f;
  const float av2   = av * L2E;
  const float negm2 = -m * L2E;

  const float* __restrict__ bi = B + i * HW;
  float part = 0.f;
#pragma unroll
  for (int j = 0; j < 11; ++j) {
    part += exp2f(fmaf(av2, bi[j * 64 + lane], negm2));
  }
#pragma unroll
  for (int off = 1; off < 64; off <<= 1)
    part += __shfl_xor(part, off, 64);
  const float inv = 1.0f / part;

  if (lane < K) {
    const float sel = (av >= 0.f) ? btop[i * K + lane] : bbot[i * K + lane];
    const float val = exp2f(fmaf(av2, sel, negm2)) * inv;
    const int n  = i / T;
    const int t  = i % T;
    const int jo = r / 44;                 // 704/16 = 44 rows per j-slice
    const int po = (r % 44) * K;
    out[((((size_t)n * K + jo) * T) + t) * HW + po + lane] = val;
  }
}

extern "C" void kernel_launch(void* const* d_in, const int* in_sizes, int n_in,
                              void* d_out, int out_size, void* d_ws, size_t ws_size,
                              hipStream_t stream) {
  (void)in_sizes; (void)n_in; (void)out_size; (void)ws_size;
  const float* x  = (const float*)d_in[0];
  const float* w1 = (const float*)d_in[1];
  const float* b1 = (const float*)d_in[2];
  const float* w2 = (const float*)d_in[3];
  const float* b2 = (const float*)d_in[4];
  // d_in[5] is top_k (=16), hardcoded as K.
  float* out = (float*)d_out;

  float* A    = (float*)d_ws;            // NS*HW
  float* B    = A + NS * HW;             // NS*HW
  float* btop = B + NS * HW;             // NS*K
  float* bbot = btop + NS * K;           // NS*K

  conv_kernel<<<124 * 11, 256, 0, stream>>>(x, w1, b1, w2, b2, A, B);
  sort_kernel<<<NS, 512, 0, stream>>>(B, btop, bbot);
  softmax_topk_kernel<<<(NS * HW) / 4, 256, 0, stream>>>(A, B, btop, bbot, out);
}